// Round 4
// baseline (176.094 us; speedup 1.0000x reference)
//
#include <hip/hip_runtime.h>
#include <hip/hip_bf16.h>
#include <cmath>

using f32x4 = __attribute__((ext_vector_type(4))) float;
using s16x8 = __attribute__((ext_vector_type(8))) short;

__device__ __forceinline__ float bf2f(unsigned short u){
  union { unsigned int i; float f; } v; v.i = ((unsigned int)u) << 16; return v.f;
}
__device__ __forceinline__ unsigned short f2bf(float f){
  union { float f; unsigned int i; } v; v.f = f;
  return (unsigned short)((v.i + 0x7FFFu + ((v.i >> 16) & 1u)) >> 16);
}

#define GLDS16(g, l) __builtin_amdgcn_global_load_lds( \
    (const __attribute__((address_space(1))) unsigned int*)(g), \
    (__attribute__((address_space(3))) unsigned int*)(l), 16, 0, 0)

// ---------------- prep: convert all small operands to bf16 ----------------
__global__ void k_prep(const float* __restrict__ Wd, const float* __restrict__ Wu,
                       const float* __restrict__ Wt, const float* __restrict__ Wf,
                       const float* __restrict__ Ap, const float* __restrict__ Bp,
                       const int* __restrict__ layerp,
                       unsigned short* __restrict__ Wdb, unsigned short* __restrict__ Wub,
                       unsigned short* __restrict__ Wtb, unsigned short* __restrict__ WB,
                       unsigned short* __restrict__ Ab, unsigned short* __restrict__ Blb){
  int idx = blockIdx.x * 256 + threadIdx.x;
  switch (blockIdx.y){
    case 0: if (idx < 24576)  Wdb[idx] = f2bf(Wd[idx]); break;
    case 1: if (idx < 73728)  Wub[idx] = f2bf(Wu[idx]); break;
    case 2: if (idx < 589824) Wtb[idx] = f2bf(Wt[idx]); break;
    case 3: if (idx < 688128){
      int n = idx / 896, c = idx - n * 896;
      WB[idx] = (c < 768) ? f2bf(Wf[n * 768 + c]) : (unsigned short)0;
    } break;
    case 4: if (idx < 28672){
      int r = idx >> 8;
      Ab[idx] = (r < 100) ? f2bf(Ap[idx]) : (unsigned short)0;
    } break;
    case 5: if (idx < 65536) Blb[idx] = f2bf(Bp[(long)(*layerp) * 65536 + idx]); break;
  }
}

// ---------------- generic 1-wave MFMA mini-GEMM: out = epi(A @ B^T + bias) ----------------
template<int EPI>
__global__ __launch_bounds__(64) void k_mm(const unsigned short* __restrict__ A, int lda,
    const unsigned short* __restrict__ B, int ldb, int K,
    const float* __restrict__ bias, unsigned short* __restrict__ out, int ldo){
  int l = threadIdx.x, l15 = l & 15, lhi = l >> 4;
  int m0 = blockIdx.x * 16, n0 = blockIdx.y * 16;
  f32x4 acc = (f32x4)0.0f;
  #pragma unroll 4
  for (int k0 = 0; k0 < K; k0 += 32){
    s16x8 a = *(const s16x8*)(A + (long)(m0 + l15) * lda + k0 + lhi * 8);
    s16x8 b = *(const s16x8*)(B + (long)(n0 + l15) * ldb + k0 + lhi * 8);
    acc = __builtin_amdgcn_mfma_f32_16x16x32_bf16(a, b, acc, 0, 0, 0);
  }
  int col = n0 + l15;
  float bv = bias ? bias[col] : 0.0f;
  #pragma unroll
  for (int r = 0; r < 4; r++){
    int row = m0 + lhi * 4 + r;
    float v = acc[r] + bv;
    if (EPI == 0){
      v = 0.5f * v * (1.0f + erff(v * 0.70710678118654752f));
      out[(long)row * ldo + col] = f2bf(v);
    } else if (EPI == 1){
      out[(long)col * ldo + row] = f2bf(v);
    } else if (EPI == 2){
      out[(long)row * ldo + col] = f2bf(v);
    } else {
      out[(long)col * 896 + 768 + row] = (row < 100) ? f2bf(v) : (unsigned short)0;
    }
  }
}

// ---------------- fused cvt + logits + softmax, SPLIT-K over 4 waves ----------------
// Block = 16 rows. Wave w computes partial logits over K-chunk w*192..+192 (6 iters),
// writes partials to LDS; after barrier wave w finishes softmax for acc component r=w.
__global__ __launch_bounds__(256) void k_attn(const float* __restrict__ xf,
    const unsigned short* __restrict__ tokensb, unsigned short* __restrict__ xb,
    unsigned short* __restrict__ Pbuf){
  __shared__ float lacc[4 * 64 * 29];   // stride 29: gcd(29,32)=1 -> conflict-free
  int tid = threadIdx.x, w = tid >> 6, l = tid & 63;
  int l15 = l & 15, lhi = l >> 4;
  long R0 = (long)blockIdx.x * 16;
  long row = R0 + l15;

  f32x4 acc[7];
  #pragma unroll
  for (int nf = 0; nf < 7; nf++) acc[nf] = (f32x4)0.0f;

  #pragma unroll 2
  for (int t = 0; t < 6; t++){
    int k0 = w * 192 + t * 32 + lhi * 8;
    f32x4 x0 = *(const f32x4*)(xf + row * 768 + k0);
    f32x4 x1 = *(const f32x4*)(xf + row * 768 + k0 + 4);
    s16x8 a;
    #pragma unroll
    for (int j = 0; j < 4; j++){ a[j] = (short)f2bf(x0[j]); a[4 + j] = (short)f2bf(x1[j]); }
    *(s16x8*)(xb + row * 768 + k0) = a;
    #pragma unroll
    for (int nf = 0; nf < 7; nf++){
      s16x8 b = *(const s16x8*)(tokensb + (nf * 16 + l15) * 768 + k0);
      acc[nf] = __builtin_amdgcn_mfma_f32_16x16x32_bf16(a, b, acc[nf], 0, 0, 0);
    }
  }

  // stash partials
  int base = (w * 64 + l) * 29;
  #pragma unroll
  for (int nf = 0; nf < 7; nf++)
    #pragma unroll
    for (int r = 0; r < 4; r++)
      lacc[base + nf * 4 + r] = acc[nf][r];
  __syncthreads();

  // wave w: sum partials for reg component r=w, softmax rows lhi*4+w
  const float sc = 0.03608439182435161f; // 768^-0.5
  float lg[7];
  #pragma unroll
  for (int nf = 0; nf < 7; nf++){
    float s = 0.f;
    #pragma unroll
    for (int w2 = 0; w2 < 4; w2++)
      s += lacc[(w2 * 64 + l) * 29 + nf * 4 + w];
    lg[nf] = s * sc;
  }
  float mx = -1e30f;
  #pragma unroll
  for (int nf = 0; nf < 7; nf++){
    int col = nf * 16 + l15;
    if (col < 100 && lg[nf] > mx) mx = lg[nf];
  }
  mx = fmaxf(mx, __shfl_xor(mx, 1));
  mx = fmaxf(mx, __shfl_xor(mx, 2));
  mx = fmaxf(mx, __shfl_xor(mx, 4));
  mx = fmaxf(mx, __shfl_xor(mx, 8));
  float p[7], sm = 0.f;
  #pragma unroll
  for (int nf = 0; nf < 7; nf++){
    int col = nf * 16 + l15;
    float v = (col < 100) ? __expf(lg[nf] - mx) : 0.f;
    p[nf] = v; sm += v;
  }
  sm += __shfl_xor(sm, 1);
  sm += __shfl_xor(sm, 2);
  sm += __shfl_xor(sm, 4);
  sm += __shfl_xor(sm, 8);
  float inv = 1.f / sm;
  long grow = R0 + lhi * 4 + w;
  #pragma unroll
  for (int nf = 0; nf < 7; nf++)
    Pbuf[grow * 128 + nf * 16 + l15] = f2bf(p[nf] * inv);
  Pbuf[grow * 128 + 112 + l15] = 0;
}

// ---------------- big GEMM: out = feats + scale*([xb|P] @ WB^T + bf) ----------------
// BM=256 BN=128 BK=64, 8 waves (4Mx2N), tribuf LDS, counted vmcnt, T2 swizzle, T5 setprio.
__global__ __launch_bounds__(512, 2) void k_gemm(const unsigned short* __restrict__ xb,
    const unsigned short* __restrict__ Pbuf, const unsigned short* __restrict__ WB,
    const float* __restrict__ bfv, const float* __restrict__ scalep,
    float* __restrict__ outf){
  extern __shared__ __align__(16) unsigned short lds[];   // 3 * (256*64 + 128*64) ushorts
  int bid = blockIdx.x;                 // 768 = 8 XCD * 96
  int sid = (bid & 7) * 96 + (bid >> 3);
  int mt = sid / 6, nt = sid - mt * 6;
  long brow = (long)mt * 256;
  int bcol = nt * 128;
  int tid = threadIdx.x, w = tid >> 6, l = tid & 63;
  int l15 = l & 15, lhi = l >> 4;
  int wr = w >> 1, wc = w & 1;
  int lrow = l >> 3;
  int lsw  = ((l & 7) ^ lrow) * 8;      // pre-swizzled source col: T2 both-sides rule

  f32x4 acc[4][4];
  #pragma unroll
  for (int m = 0; m < 4; m++)
    #pragma unroll
    for (int n = 0; n < 4; n++) acc[m][n] = (f32x4)0.0f;

  #define STAGE(BUF, T) { \
    int koff = (T) * 64; \
    _Pragma("unroll") \
    for (int i = 0; i < 4; i++){ \
      int r = (w * 4 + i) * 8 + lrow; \
      const unsigned short* ga = ((T) < 12) \
        ? xb   + (brow + r) * 768 + koff + lsw \
        : Pbuf + (brow + r) * 128 + ((T) - 12) * 64 + lsw; \
      GLDS16(ga, lds + (BUF) * 24576 + (w * 4 + i) * 512); \
    } \
    _Pragma("unroll") \
    for (int i = 0; i < 2; i++){ \
      int r = (w * 2 + i) * 8 + lrow; \
      const unsigned short* gb = WB + (long)(bcol + r) * 896 + koff + lsw; \
      GLDS16(gb, lds + (BUF) * 24576 + 16384 + (w * 2 + i) * 512); \
    } }

  STAGE(0, 0);
  STAGE(1, 1);
  for (int t = 0; t < 14; t++){
    if (t < 13) asm volatile("s_waitcnt vmcnt(6)" ::: "memory");
    else        asm volatile("s_waitcnt vmcnt(0)" ::: "memory");
    __builtin_amdgcn_s_barrier();
    if (t < 12){
      int nb = t + 2 - ((t + 2) >= 3 ? 3 : 0); nb -= (nb >= 3 ? 3 : 0);
      STAGE(nb, t + 2);
    }
    const unsigned short* Ab = lds + (t % 3) * 24576;
    const unsigned short* Bb = Ab + 16384;
    __builtin_amdgcn_s_setprio(1);
    #pragma unroll
    for (int kk = 0; kk < 2; kk++){
      s16x8 a[4], b[4];
      #pragma unroll
      for (int m = 0; m < 4; m++){
        int ar = wr * 64 + m * 16 + l15;
        int xoff = (kk * 64 + lhi * 16) ^ ((ar & 7) << 4);
        a[m] = *(const s16x8*)(Ab + ar * 64 + (xoff >> 1));
      }
      #pragma unroll
      for (int n = 0; n < 4; n++){
        int br = wc * 64 + n * 16 + l15;
        int xoff = (kk * 64 + lhi * 16) ^ ((br & 7) << 4);
        b[n] = *(const s16x8*)(Bb + br * 64 + (xoff >> 1));
      }
      #pragma unroll
      for (int m = 0; m < 4; m++)
        #pragma unroll
        for (int n = 0; n < 4; n++)
          acc[m][n] = __builtin_amdgcn_mfma_f32_16x16x32_bf16(a[m], b[n], acc[m][n], 0, 0, 0);
    }
    __builtin_amdgcn_s_setprio(0);
  }
  #undef STAGE

  float scale = *scalep;
  #pragma unroll
  for (int m = 0; m < 4; m++){
    #pragma unroll
    for (int n = 0; n < 4; n++){
      int gcol = bcol + wc * 64 + n * 16 + l15;
      float bias = bfv[gcol];
      #pragma unroll
      for (int r = 0; r < 4; r++){
        long grow = brow + wr * 64 + m * 16 + lhi * 4 + r;
        float feat = bf2f(xb[grow * 768 + gcol]);
        outf[grow * 768 + gcol] = feat + scale * (acc[m][n][r] + bias);
      }
    }
  }
}

extern "C" void kernel_launch(void* const* d_in, const int* in_sizes, int n_in,
                              void* d_out, int out_size, void* d_ws, size_t ws_size,
                              hipStream_t stream) {
  const float* x   = (const float*)d_in[0];
  const float* Wd  = (const float*)d_in[1];
  const float* bd  = (const float*)d_in[2];
  const float* Wu  = (const float*)d_in[3];
  const float* bu  = (const float*)d_in[4];
  const float* Wt  = (const float*)d_in[5];
  const float* bt  = (const float*)d_in[6];
  const float* Wf  = (const float*)d_in[7];
  const float* bfv = (const float*)d_in[8];
  const float* Ap  = (const float*)d_in[9];
  const float* Bp  = (const float*)d_in[10];
  const float* scalep = (const float*)d_in[11];
  const int* layerp   = (const int*)d_in[12];
  float* out = (float*)d_out;

  char* ws = (char*)d_ws;
  unsigned short* xb      = (unsigned short*)(ws);              // 50,331,648
  unsigned short* Pbuf    = (unsigned short*)(ws + 50331648);   //  8,388,608
  unsigned short* WB      = (unsigned short*)(ws + 58720256);   //  1,376,256 (768 x 896)
  unsigned short* Wtb     = (unsigned short*)(ws + 60096512);   //  1,179,648 (768 x 768)
  unsigned short* tokensb = (unsigned short*)(ws + 61276160);   //    172,032 (112 x 768)
  unsigned short* t2fb    = (unsigned short*)(ws + 61448192);   //    172,032 (112 x 768)
  unsigned short* Ab      = (unsigned short*)(ws + 61620224);   //     57,344 (112 x 256)
  unsigned short* Blb     = (unsigned short*)(ws + 61677568);   //    131,072 (256 x 256)
  unsigned short* Wdb     = (unsigned short*)(ws + 61808640);   //     49,152 ( 96 x 256)
  unsigned short* Wub     = (unsigned short*)(ws + 61857792);   //    147,456 (768 x  96)
  unsigned short* hb      = (unsigned short*)(ws + 62005248);   //     49,152 (256 x  96)
  unsigned short* Bfmt    = (unsigned short*)(ws + 62054400);   //    393,216 (768 x 256, Bf^T)

  const float* xf = x + 32 * 768;   // feats (skip cls rows)
  float* outf = out + 32 * 768;

  static int lds_attr_set = 0;
  if (!lds_attr_set){
    hipFuncSetAttribute((const void*)k_gemm, hipFuncAttributeMaxDynamicSharedMemorySize, 147456);
    lds_attr_set = 1;
  }

  // cls passthrough
  hipMemcpyAsync(d_out, d_in[0], 32 * 768 * sizeof(float), hipMemcpyDeviceToDevice, stream);

  k_prep<<<dim3(2688, 6), 256, 0, stream>>>(Wd, Wu, Wt, Wf, Ap, Bp, layerp,
                                            Wdb, Wub, Wtb, WB, Ab, Blb);
  k_mm<0><<<dim3(16, 6),  64, 0, stream>>>(Blb, 256, Wdb, 256, 256, bd, hb, 96);
  k_mm<1><<<dim3(16, 48), 64, 0, stream>>>(hb, 96, Wub, 96, 96, bu, Bfmt, 256);
  k_mm<2><<<dim3(7, 48),  64, 0, stream>>>(Ab, 256, Bfmt, 256, 256, nullptr, tokensb, 768);
  k_mm<2><<<dim3(7, 48),  64, 0, stream>>>(tokensb, 768, Wtb, 768, 768, bt, t2fb, 768);
  k_mm<3><<<dim3(7, 48),  64, 0, stream>>>(t2fb, 768, WB, 896, 768, nullptr, WB, 0);

  k_attn<<<2048, 256, 0, stream>>>(xf, tokensb, xb, Pbuf);
  k_gemm<<<768, 512, 147456, stream>>>(xb, Pbuf, WB, bfv, scalep, outf);
}

// Round 5
// 139.886 us; speedup vs baseline: 1.2588x; 1.2588x over previous
//
#include <hip/hip_runtime.h>
#include <hip/hip_bf16.h>
#include <cmath>

using f32x4 = __attribute__((ext_vector_type(4))) float;
using s16x8 = __attribute__((ext_vector_type(8))) short;
using u16x4 = __attribute__((ext_vector_type(4))) unsigned short;

__device__ __forceinline__ float bf2f(unsigned short u){
  union { unsigned int i; float f; } v; v.i = ((unsigned int)u) << 16; return v.f;
}
__device__ __forceinline__ unsigned short f2bf(float f){
  union { float f; unsigned int i; } v; v.f = f;
  return (unsigned short)((v.i + 0x7FFFu + ((v.i >> 16) & 1u)) >> 16);
}

#define GLDS16(g, l) __builtin_amdgcn_global_load_lds( \
    (const __attribute__((address_space(1))) unsigned int*)(g), \
    (__attribute__((address_space(3))) unsigned int*)(l), 16, 0, 0)

// ---------------- prep: convert all small operands to bf16 ----------------
__global__ void k_prep(const float* __restrict__ Wd, const float* __restrict__ Wu,
                       const float* __restrict__ Wt, const float* __restrict__ Wf,
                       const float* __restrict__ Ap, const float* __restrict__ Bp,
                       const int* __restrict__ layerp,
                       unsigned short* __restrict__ Wdb, unsigned short* __restrict__ Wub,
                       unsigned short* __restrict__ Wtb, unsigned short* __restrict__ WB,
                       unsigned short* __restrict__ Ab, unsigned short* __restrict__ Blb){
  int idx = blockIdx.x * 256 + threadIdx.x;
  switch (blockIdx.y){
    case 0: if (idx < 24576)  Wdb[idx] = f2bf(Wd[idx]); break;
    case 1: if (idx < 73728)  Wub[idx] = f2bf(Wu[idx]); break;
    case 2: if (idx < 589824) Wtb[idx] = f2bf(Wt[idx]); break;
    case 3: if (idx < 688128){
      int n = idx / 896, c = idx - n * 896;
      WB[idx] = (c < 768) ? f2bf(Wf[n * 768 + c]) : (unsigned short)0;
    } break;
    case 4: if (idx < 28672){
      int r = idx >> 8;
      Ab[idx] = (r < 100) ? f2bf(Ap[idx]) : (unsigned short)0;
    } break;
    case 5: if (idx < 65536) Blb[idx] = f2bf(Bp[(long)(*layerp) * 65536 + idx]); break;
  }
}

// ---------------- generic 1-wave MFMA mini-GEMM: out = epi(A @ B^T + bias) ----------------
template<int EPI>
__global__ __launch_bounds__(64) void k_mm(const unsigned short* __restrict__ A, int lda,
    const unsigned short* __restrict__ B, int ldb, int K,
    const float* __restrict__ bias, unsigned short* __restrict__ out, int ldo){
  int l = threadIdx.x, l15 = l & 15, lhi = l >> 4;
  int m0 = blockIdx.x * 16, n0 = blockIdx.y * 16;
  f32x4 acc = (f32x4)0.0f;
  #pragma unroll 4
  for (int k0 = 0; k0 < K; k0 += 32){
    s16x8 a = *(const s16x8*)(A + (long)(m0 + l15) * lda + k0 + lhi * 8);
    s16x8 b = *(const s16x8*)(B + (long)(n0 + l15) * ldb + k0 + lhi * 8);
    acc = __builtin_amdgcn_mfma_f32_16x16x32_bf16(a, b, acc, 0, 0, 0);
  }
  int col = n0 + l15;
  float bv = bias ? bias[col] : 0.0f;
  #pragma unroll
  for (int r = 0; r < 4; r++){
    int row = m0 + lhi * 4 + r;
    float v = acc[r] + bv;
    if (EPI == 0){
      v = 0.5f * v * (1.0f + erff(v * 0.70710678118654752f));
      out[(long)row * ldo + col] = f2bf(v);
    } else if (EPI == 1){
      out[(long)col * ldo + row] = f2bf(v);
    } else if (EPI == 2){
      out[(long)row * ldo + col] = f2bf(v);
    } else {
      out[(long)col * 896 + 768 + row] = (row < 100) ? f2bf(v) : (unsigned short)0;
    }
  }
}

// ---------------- fused cvt + logits + softmax, LDS-staged GEMM form ----------------
// Block: 32 rows, 4 waves. Wave (rg,kh): row-group rg*16, K-half kh*384.
// X tile (32x128 f32 cols -> bf16) reg-staged coalesced w/ XOR-swizzled LDS writes;
// T tile (112x128 bf16) via global_load_lds with pre-swizzled global source (rule 21).
__global__ __launch_bounds__(256, 4) void k_attn(const float* __restrict__ xf,
    const unsigned short* __restrict__ tokensb, unsigned short* __restrict__ xb,
    unsigned short* __restrict__ Pbuf){
  __shared__ __align__(16) char smem[40960];
  unsigned short* Xs = (unsigned short*)smem;            // [32][128] us, swizzled
  unsigned short* Ts = (unsigned short*)(smem + 8192);   // [112][128] us, swizzled
  float* st = (float*)smem;                              // post-loop stash overlay

  int tid = threadIdx.x, w = tid >> 6, l = tid & 63;
  int l15 = l & 15, lhi = l >> 4;
  int rg = w >> 1, kh = w & 1;
  long R0 = (long)blockIdx.x * 32;

  f32x4 acc[7];
  #pragma unroll
  for (int nf = 0; nf < 7; nf++) acc[nf] = (f32x4)0.0f;

  int xrow = tid >> 5;           // 0..7 (8 rows per round)
  int xcol = (tid & 31) * 4;     // f32 col within 128-chunk (coalesced)

  for (int it = 0; it < 6; it++){
    // stage T: 7 gl_lds per wave; dest linear, source col pre-swizzled within 256B row
    #pragma unroll
    for (int i = 0; i < 7; i++){
      int g = (w * 7 + i) * 4 + (l >> 4);          // token row 0..111
      const unsigned short* src = tokensb + (long)g * 768 + it * 128
                                + (((l & 15) * 8) ^ ((g & 7) << 3));
      GLDS16(src, Ts + (w * 7 + i) * 512);
    }
    // stage X: coalesced f32 reads, cvt, coalesced xb store + swizzled LDS write
    #pragma unroll
    for (int rnd = 0; rnd < 4; rnd++){
      int row = rnd * 8 + xrow;
      f32x4 v = *(const f32x4*)(xf + (R0 + row) * 768 + it * 128 + xcol);
      u16x4 c;
      #pragma unroll
      for (int j = 0; j < 4; j++) c[j] = f2bf(v[j]);
      *(u16x4*)(xb + (R0 + row) * 768 + it * 128 + xcol) = c;
      *(u16x4*)(Xs + row * 128 + (xcol ^ ((row & 7) << 3))) = c;
    }
    __syncthreads();
    // compute: wave (rg,kh) -> rows rg*16.., cols kh*64.. (us) of the 128-us tiles
    int ar = rg * 16 + l15;
    #pragma unroll
    for (int kk = 0; kk < 2; kk++){
      int coff = kh * 64 + kk * 32 + lhi * 8;
      s16x8 a = *(const s16x8*)(Xs + ar * 128 + (coff ^ ((ar & 7) << 3)));
      #pragma unroll
      for (int nf = 0; nf < 7; nf++){
        int br = nf * 16 + l15;
        s16x8 b = *(const s16x8*)(Ts + br * 128 + (coff ^ ((br & 7) << 3)));
        acc[nf] = __builtin_amdgcn_mfma_f32_16x16x32_bf16(a, b, acc[nf], 0, 0, 0);
      }
    }
    __syncthreads();
  }

  // split-K combine: kh=1 stashes, kh=0 sums + softmax
  if (kh == 1){
    int widx = rg * 64 + l;
    #pragma unroll
    for (int nf = 0; nf < 7; nf++)
      #pragma unroll
      for (int r = 0; r < 4; r++)
        st[widx * 29 + nf * 4 + r] = acc[nf][r];
  }
  __syncthreads();
  if (kh == 0){
    const float sc = 0.03608439182435161f; // 768^-0.5
    int widx = rg * 64 + l;
    float lg[4][7];
    #pragma unroll
    for (int nf = 0; nf < 7; nf++)
      #pragma unroll
      for (int r = 0; r < 4; r++)
        lg[r][nf] = (acc[nf][r] + st[widx * 29 + nf * 4 + r]) * sc;
    #pragma unroll
    for (int r = 0; r < 4; r++){
      float mx = -1e30f;
      #pragma unroll
      for (int nf = 0; nf < 7; nf++){
        int col = nf * 16 + l15;
        if (col < 100 && lg[r][nf] > mx) mx = lg[r][nf];
      }
      mx = fmaxf(mx, __shfl_xor(mx, 1));
      mx = fmaxf(mx, __shfl_xor(mx, 2));
      mx = fmaxf(mx, __shfl_xor(mx, 4));
      mx = fmaxf(mx, __shfl_xor(mx, 8));
      float p[7], sm = 0.f;
      #pragma unroll
      for (int nf = 0; nf < 7; nf++){
        int col = nf * 16 + l15;
        float v = (col < 100) ? __expf(lg[r][nf] - mx) : 0.f;
        p[nf] = v; sm += v;
      }
      sm += __shfl_xor(sm, 1);
      sm += __shfl_xor(sm, 2);
      sm += __shfl_xor(sm, 4);
      sm += __shfl_xor(sm, 8);
      float inv = 1.f / sm;
      long grow = R0 + rg * 16 + lhi * 4 + r;
      #pragma unroll
      for (int nf = 0; nf < 7; nf++)
        Pbuf[grow * 128 + nf * 16 + l15] = f2bf(p[nf] * inv);
      Pbuf[grow * 128 + 112 + l15] = 0;
    }
  }
}

// ---------------- big GEMM: out = feats + scale*([xb|P] @ WB^T + bf) ----------------
// BM=256 BN=128 BK=64, 8 waves (4Mx2N), tribuf LDS, counted vmcnt, T2 swizzle, T5 setprio.
__global__ __launch_bounds__(512, 2) void k_gemm(const unsigned short* __restrict__ xb,
    const unsigned short* __restrict__ Pbuf, const unsigned short* __restrict__ WB,
    const float* __restrict__ bfv, const float* __restrict__ scalep,
    float* __restrict__ outf){
  extern __shared__ __align__(16) unsigned short lds[];   // 3 * (256*64 + 128*64) ushorts
  int bid = blockIdx.x;                 // 768 = 8 XCD * 96
  int sid = (bid & 7) * 96 + (bid >> 3);
  int mt = sid / 6, nt = sid - mt * 6;
  long brow = (long)mt * 256;
  int bcol = nt * 128;
  int tid = threadIdx.x, w = tid >> 6, l = tid & 63;
  int l15 = l & 15, lhi = l >> 4;
  int wr = w >> 1, wc = w & 1;
  int lrow = l >> 3;
  int lsw  = ((l & 7) ^ lrow) * 8;      // pre-swizzled source col: T2 both-sides rule

  f32x4 acc[4][4];
  #pragma unroll
  for (int m = 0; m < 4; m++)
    #pragma unroll
    for (int n = 0; n < 4; n++) acc[m][n] = (f32x4)0.0f;

  #define STAGE(BUF, T) { \
    int koff = (T) * 64; \
    _Pragma("unroll") \
    for (int i = 0; i < 4; i++){ \
      int r = (w * 4 + i) * 8 + lrow; \
      const unsigned short* ga = ((T) < 12) \
        ? xb   + (brow + r) * 768 + koff + lsw \
        : Pbuf + (brow + r) * 128 + ((T) - 12) * 64 + lsw; \
      GLDS16(ga, lds + (BUF) * 24576 + (w * 4 + i) * 512); \
    } \
    _Pragma("unroll") \
    for (int i = 0; i < 2; i++){ \
      int r = (w * 2 + i) * 8 + lrow; \
      const unsigned short* gb = WB + (long)(bcol + r) * 896 + koff + lsw; \
      GLDS16(gb, lds + (BUF) * 24576 + 16384 + (w * 2 + i) * 512); \
    } }

  STAGE(0, 0);
  STAGE(1, 1);
  for (int t = 0; t < 14; t++){
    if (t < 13) asm volatile("s_waitcnt vmcnt(6)" ::: "memory");
    else        asm volatile("s_waitcnt vmcnt(0)" ::: "memory");
    __builtin_amdgcn_s_barrier();
    if (t < 12){
      int nb = t + 2 - ((t + 2) >= 3 ? 3 : 0); nb -= (nb >= 3 ? 3 : 0);
      STAGE(nb, t + 2);
    }
    const unsigned short* Ab = lds + (t % 3) * 24576;
    const unsigned short* Bb = Ab + 16384;
    __builtin_amdgcn_s_setprio(1);
    #pragma unroll
    for (int kk = 0; kk < 2; kk++){
      s16x8 a[4], b[4];
      #pragma unroll
      for (int m = 0; m < 4; m++){
        int ar = wr * 64 + m * 16 + l15;
        int xoff = (kk * 64 + lhi * 16) ^ ((ar & 7) << 4);
        a[m] = *(const s16x8*)(Ab + ar * 64 + (xoff >> 1));
      }
      #pragma unroll
      for (int n = 0; n < 4; n++){
        int br = wc * 64 + n * 16 + l15;
        int xoff = (kk * 64 + lhi * 16) ^ ((br & 7) << 4);
        b[n] = *(const s16x8*)(Bb + br * 64 + (xoff >> 1));
      }
      #pragma unroll
      for (int m = 0; m < 4; m++)
        #pragma unroll
        for (int n = 0; n < 4; n++)
          acc[m][n] = __builtin_amdgcn_mfma_f32_16x16x32_bf16(a[m], b[n], acc[m][n], 0, 0, 0);
    }
    __builtin_amdgcn_s_setprio(0);
  }
  #undef STAGE

  float scale = *scalep;
  #pragma unroll
  for (int m = 0; m < 4; m++){
    #pragma unroll
    for (int n = 0; n < 4; n++){
      int gcol = bcol + wc * 64 + n * 16 + l15;
      float bias = bfv[gcol];
      #pragma unroll
      for (int r = 0; r < 4; r++){
        long grow = brow + wr * 64 + m * 16 + lhi * 4 + r;
        float feat = bf2f(xb[grow * 768 + gcol]);
        outf[grow * 768 + gcol] = feat + scale * (acc[m][n][r] + bias);
      }
    }
  }
}

extern "C" void kernel_launch(void* const* d_in, const int* in_sizes, int n_in,
                              void* d_out, int out_size, void* d_ws, size_t ws_size,
                              hipStream_t stream) {
  const float* x   = (const float*)d_in[0];
  const float* Wd  = (const float*)d_in[1];
  const float* bd  = (const float*)d_in[2];
  const float* Wu  = (const float*)d_in[3];
  const float* bu  = (const float*)d_in[4];
  const float* Wt  = (const float*)d_in[5];
  const float* bt  = (const float*)d_in[6];
  const float* Wf  = (const float*)d_in[7];
  const float* bfv = (const float*)d_in[8];
  const float* Ap  = (const float*)d_in[9];
  const float* Bp  = (const float*)d_in[10];
  const float* scalep = (const float*)d_in[11];
  const int* layerp   = (const int*)d_in[12];
  float* out = (float*)d_out;

  char* ws = (char*)d_ws;
  unsigned short* xb      = (unsigned short*)(ws);              // 50,331,648
  unsigned short* Pbuf    = (unsigned short*)(ws + 50331648);   //  8,388,608
  unsigned short* WB      = (unsigned short*)(ws + 58720256);   //  1,376,256 (768 x 896)
  unsigned short* Wtb     = (unsigned short*)(ws + 60096512);   //  1,179,648 (768 x 768)
  unsigned short* tokensb = (unsigned short*)(ws + 61276160);   //    172,032 (112 x 768)
  unsigned short* t2fb    = (unsigned short*)(ws + 61448192);   //    172,032 (112 x 768)
  unsigned short* Ab      = (unsigned short*)(ws + 61620224);   //     57,344 (112 x 256)
  unsigned short* Blb     = (unsigned short*)(ws + 61677568);   //    131,072 (256 x 256)
  unsigned short* Wdb     = (unsigned short*)(ws + 61808640);   //     49,152 ( 96 x 256)
  unsigned short* Wub     = (unsigned short*)(ws + 61857792);   //    147,456 (768 x  96)
  unsigned short* hb      = (unsigned short*)(ws + 62005248);   //     49,152 (256 x  96)
  unsigned short* Bfmt    = (unsigned short*)(ws + 62054400);   //    393,216 (768 x 256, Bf^T)

  const float* xf = x + 32 * 768;   // feats (skip cls rows)
  float* outf = out + 32 * 768;

  static int lds_attr_set = 0;
  if (!lds_attr_set){
    hipFuncSetAttribute((const void*)k_gemm, hipFuncAttributeMaxDynamicSharedMemorySize, 147456);
    lds_attr_set = 1;
  }

  // cls passthrough
  hipMemcpyAsync(d_out, d_in[0], 32 * 768 * sizeof(float), hipMemcpyDeviceToDevice, stream);

  k_prep<<<dim3(2688, 6), 256, 0, stream>>>(Wd, Wu, Wt, Wf, Ap, Bp, layerp,
                                            Wdb, Wub, Wtb, WB, Ab, Blb);
  k_mm<0><<<dim3(16, 6),  64, 0, stream>>>(Blb, 256, Wdb, 256, 256, bd, hb, 96);
  k_mm<1><<<dim3(16, 48), 64, 0, stream>>>(hb, 96, Wub, 96, 96, bu, Bfmt, 256);
  k_mm<2><<<dim3(7, 48),  64, 0, stream>>>(Ab, 256, Bfmt, 256, 256, nullptr, tokensb, 768);
  k_mm<2><<<dim3(7, 48),  64, 0, stream>>>(tokensb, 768, Wtb, 768, 768, bt, t2fb, 768);
  k_mm<3><<<dim3(7, 48),  64, 0, stream>>>(t2fb, 768, WB, 896, 768, nullptr, WB, 0);

  k_attn<<<1024, 256, 0, stream>>>(xf, tokensb, xb, Pbuf);
  k_gemm<<<768, 512, 147456, stream>>>(xb, Pbuf, WB, bfv, scalep, outf);
}